// Round 5
// baseline (222.263 us; speedup 1.0000x reference)
//
#include <hip/hip_runtime.h>
#include <cstdint>

typedef float float4v __attribute__((ext_vector_type(4)));

__device__ __forceinline__ uint32_t mono32(float x) {
    int32_t b = __float_as_int(x);
    return (uint32_t)(b ^ ((b >> 31) | 0x80000000));
}

// async global->LDS, 16B/lane; LDS dest = wave-uniform base + lane*16
__device__ __forceinline__ void gll16(const float* g, float* l) {
    __builtin_amdgcn_global_load_lds((const __attribute__((address_space(1))) void*)g,
                                     (__attribute__((address_space(3))) void*)l, 16, 0, 0);
}

// One wave per block, one thread per row, 64 rows, ONE drain (R3 structure).
// LDS holds ONLY the inputs tile (16 KB -> 10 blocks/CU). Proven swizzle:
//   stage instr k, lane l -> unit p = 64k+l holds (row r = p>>4, quad (p&15)^(r&7))
//     => each instr reads 4 full rows = 1 KB (coalesced)
//   owner read: thread t, quad q -> unit 16t + (q^(t&7))  (conflict-negligible, R3-measured)
// Noise: direct per-row dwordx4 loads into registers (line-completing pattern,
// HBM-neutral per R4's store evidence), same single vmcnt drain.
__global__ __launch_bounds__(64, 2)
void gumbel_topk_softmax_kernel(const float* __restrict__ gin,
                                const float* __restrict__ gnz,
                                float* __restrict__ gout) {
    __shared__ __align__(16) float bufA[64 * 64];   // inputs tile only, 16 KB

    const int t    = threadIdx.x;        // 0..63 = local row
    const int row0 = blockIdx.x * 64;
    const int sw   = t & 7;

    // ---- issue burst: 16 x global_load_lds (inputs) + 16 x dwordx4 (noise) ----
#pragma unroll
    for (int k = 0; k < 16; ++k) {
        const int p = k * 64 + t;
        const int r = p >> 4;
        const int j = (p & 15) ^ (r & 7);
        gll16(gin + (uint32_t)(row0 + r) * 64u + (uint32_t)j * 4u, &bufA[k * 256]);
    }
    const float4v* nrow = (const float4v*)(gnz + (size_t)(row0 + t) * 64);
    float4v nz[16];                      // own row's noise (static-indexed)
#pragma unroll
    for (int q = 0; q < 16; ++q) nz[q] = nrow[q];

    __syncthreads();    // single wave: one vmcnt(0) drain for everything

    // ---- consume own row: bubble top-8 on z = in + noise ----
    float vin[64];      // original inputs (static-indexed)
    float keys[64];     // z values (static-indexed)
    float heap[8];
#pragma unroll
    for (int q = 0; q < 8; ++q) heap[q] = -INFINITY;

#pragma unroll
    for (int q = 0; q < 16; ++q) {
        const int u = 16 * t + (q ^ sw);
        float4v a = *(const float4v*)&bufA[u * 4];
#pragma unroll
        for (int i = 0; i < 4; ++i) {
            const int j = q * 4 + i;
            float s = a[i] + nz[q][i];
            vin[j]  = a[i];
            keys[j] = s;
#pragma unroll
            for (int u8 = 0; u8 < 8; ++u8) {
                float h = heap[u8];
                heap[u8] = fmaxf(h, s);
                s        = fminf(h, s);
            }
        }
    }

    // ---- selection: threshold fast path, exact u64 fallback on f32 ties ----
    const float T = heap[7];
    int cnt = 0;
    uint32_t mlo = 0u, mhi = 0u;
#pragma unroll
    for (int j = 0; j < 64; ++j) {
        bool ge = keys[j] >= T;
        cnt += ge ? 1 : 0;
        if (j < 32) mlo |= ge ? (1u << j) : 0u;
        else        mhi |= ge ? (1u << (j - 32)) : 0u;
    }
    if (cnt != 8) {
        // cold (~3e-5 of rows): f32 tie at rank-8 boundary. Exact f64 order via
        // u64 key = [mono(s) | mono(2Sum residual)>>6 | 63-j]; noise from regs.
        unsigned long long h8[8];
#pragma unroll
        for (int q = 0; q < 8; ++q) h8[q] = 0ull;
#pragma unroll
        for (int j = 0; j < 64; ++j) {
            float a = vin[j], b = nz[j >> 2][j & 3];
            float s  = a + b;
            float ap = s - b;
            float bp = s - ap;
            float res = (a - ap) + (b - bp);
            unsigned long long key = ((unsigned long long)mono32(s) << 32)
                                   | ((unsigned long long)(mono32(res) >> 6) << 6)
                                   | (unsigned long long)(63 - j);
#pragma unroll
            for (int q = 0; q < 8; ++q) {
                unsigned long long hq = h8[q];
                unsigned long long mx = key > hq ? key : hq;
                key   = key > hq ? hq : key;
                h8[q] = mx;
            }
        }
        mlo = mhi = 0u;
#pragma unroll
        for (int q = 0; q < 8; ++q) {
            int j = 63 - (int)(h8[q] & 63ull);
            if (j < 32) mlo |= 1u << j;
            else        mhi |= 1u << (j - 32);
        }
    }

    // ---- softmax over selected ORIGINAL inputs (no shift: |in| < ~6) ----
    float ssum = 0.f;
#pragma unroll
    for (int j = 0; j < 64; ++j) {
        uint32_t bit = (j < 32 ? (mlo >> j) : (mhi >> (j - 32))) & 1u;
        float ev = __expf(vin[j]) * (float)bit;
        ssum += ev;
        vin[j] = ev;
    }
    const float inv = 1.0f / ssum;

    // ---- direct row stores (R4-proven: WRITE_SIZE stays ~ideal) ----
    float4v* orow = (float4v*)(gout + (size_t)(row0 + t) * 64);
#pragma unroll
    for (int q = 0; q < 16; ++q) {
        float4v v;
#pragma unroll
        for (int i = 0; i < 4; ++i) v[i] = vin[q * 4 + i] * inv;
        orow[q] = v;
    }
}

extern "C" void kernel_launch(void* const* d_in, const int* in_sizes, int n_in,
                              void* d_out, int out_size, void* d_ws, size_t ws_size,
                              hipStream_t stream) {
    const float* gin = (const float*)d_in[0];
    const float* gnz = (const float*)d_in[1];
    float* gout = (float*)d_out;
    const int nrows = in_sizes[0] / 64;        // 1,048,576
    const int grid  = nrows / 64;              // 16384 single-wave blocks
    gumbel_topk_softmax_kernel<<<grid, 64, 0, stream>>>(gin, gnz, gout);
}

// Round 6
// 160.914 us; speedup vs baseline: 1.3813x; 1.3813x over previous
//
#include <hip/hip_runtime.h>
#include <cstdint>

typedef float float4v __attribute__((ext_vector_type(4)));

__device__ __forceinline__ uint32_t mono32(float x) {
    int32_t b = __float_as_int(x);
    return (uint32_t)(b ^ ((b >> 31) | 0x80000000));
}

// 4 lanes per row (lane c owns experts 16c..16c+15), 64 rows per 256-block.
// All global traffic perfectly coalesced; no LDS, no barriers. Row-wide top-8
// via per-lane bubble + 2-round bitonic merge over shfl_xor(1,2).
__global__ __launch_bounds__(256, 4)
void gumbel_topk_softmax_kernel(const float* __restrict__ gin,
                                const float* __restrict__ gnz,
                                float* __restrict__ gout) {
    const int t   = threadIdx.x;
    const int c   = t & 3;                                   // quarter of row
    const size_t row = (size_t)blockIdx.x * 64 + (t >> 2);
    const size_t base = row * 64 + (size_t)c * 16;

    const float4v* a4 = (const float4v*)(gin + base);
    const float4v* b4 = (const float4v*)(gnz + base);

    float4v vin[4], vnz[4];
#pragma unroll
    for (int q = 0; q < 4; ++q) vin[q] = a4[q];
#pragma unroll
    for (int q = 0; q < 4; ++q) vnz[q] = b4[q];

    // ---- per-lane bubble top-8 of its 16 z values ----
    float keys[16];
    float heap[8];
#pragma unroll
    for (int u = 0; u < 8; ++u) heap[u] = -INFINITY;
#pragma unroll
    for (int q = 0; q < 4; ++q)
#pragma unroll
        for (int i = 0; i < 4; ++i) {
            float s = vin[q][i] + vnz[q][i];
            keys[q * 4 + i] = s;
#pragma unroll
            for (int u = 0; u < 8; ++u) {
                float h = heap[u];
                heap[u] = fmaxf(h, s);
                s       = fminf(h, s);
            }
        }

    // ---- merge the 4 lanes' sorted-desc lists: top-8 of the row ----
#define CEX(A, B) { float mx = fmaxf(heap[A], heap[B]);                       \
                    float mn = fminf(heap[A], heap[B]);                       \
                    heap[A] = mx; heap[B] = mn; }
#pragma unroll
    for (int m = 1; m <= 2; m <<= 1) {
        float part[8];
#pragma unroll
        for (int u = 0; u < 8; ++u) part[u] = __shfl_xor(heap[7 - u], m);
#pragma unroll
        for (int u = 0; u < 8; ++u) heap[u] = fmaxf(heap[u], part[u]);
        // bitonic clean -> descending
        CEX(0, 4) CEX(1, 5) CEX(2, 6) CEX(3, 7)
        CEX(0, 2) CEX(1, 3) CEX(4, 6) CEX(5, 7)
        CEX(0, 1) CEX(2, 3) CEX(4, 5) CEX(6, 7)
    }
#undef CEX

    // ---- threshold selection + row-wide count ----
    const float T = heap[7];
    uint32_t m16 = 0u;
    int cnt = 0;
#pragma unroll
    for (int j = 0; j < 16; ++j) {
        bool ge = keys[j] >= T;
        cnt += ge ? 1 : 0;
        m16 |= ge ? (1u << j) : 0u;
    }
    cnt += __shfl_xor(cnt, 1);
    cnt += __shfl_xor(cnt, 2);

    if (cnt != 8) {
        // cold (~3e-5 of rows): f32 tie at rank-8. Exact f64 order via u64 key
        // [mono(s) | mono(2Sum residual)>>6 | 63-j]; row re-read from global
        // (L2-hot), redundantly on each of the row's 4 lanes.
        unsigned long long h8[8];
#pragma unroll
        for (int u = 0; u < 8; ++u) h8[u] = 0ull;
        const float* ar = gin + row * 64;
        const float* br = gnz + row * 64;
#pragma unroll
        for (int j = 0; j < 64; ++j) {
            float a = ar[j], b = br[j];
            float s  = a + b;
            float ap = s - b;
            float bp = s - ap;
            float res = (a - ap) + (b - bp);
            unsigned long long key = ((unsigned long long)mono32(s) << 32)
                                   | ((unsigned long long)(mono32(res) >> 6) << 6)
                                   | (unsigned long long)(63 - j);
#pragma unroll
            for (int u = 0; u < 8; ++u) {
                unsigned long long hq = h8[u];
                unsigned long long mx = key > hq ? key : hq;
                key   = key > hq ? hq : key;
                h8[u] = mx;
            }
        }
        unsigned long long mask64 = 0ull;
#pragma unroll
        for (int u = 0; u < 8; ++u) mask64 |= 1ull << (63 - (int)(h8[u] & 63ull));
        m16 = (uint32_t)((mask64 >> (c * 16)) & 0xFFFFull);
    }

    // ---- softmax over selected ORIGINAL inputs (no shift: |in| < ~6) ----
    float4v ev[4];
    float ssum = 0.f;
#pragma unroll
    for (int q = 0; q < 4; ++q)
#pragma unroll
        for (int i = 0; i < 4; ++i) {
            float e = __expf(vin[q][i]) * (float)((m16 >> (q * 4 + i)) & 1u);
            ev[q][i] = e;
            ssum += e;
        }
    ssum += __shfl_xor(ssum, 1);
    ssum += __shfl_xor(ssum, 2);
    const float inv = 1.0f / ssum;

    // ---- coalesced stores ----
    float4v* o4 = (float4v*)(gout + base);
#pragma unroll
    for (int q = 0; q < 4; ++q) {
        float4v v;
#pragma unroll
        for (int i = 0; i < 4; ++i) v[i] = ev[q][i] * inv;
        o4[q] = v;
    }
}

extern "C" void kernel_launch(void* const* d_in, const int* in_sizes, int n_in,
                              void* d_out, int out_size, void* d_ws, size_t ws_size,
                              hipStream_t stream) {
    const float* gin = (const float*)d_in[0];
    const float* gnz = (const float*)d_in[1];
    float* gout = (float*)d_out;
    const int nrows = in_sizes[0] / 64;        // 1,048,576
    const int grid  = nrows / 64;              // 16384 blocks x 256 threads
    gumbel_topk_softmax_kernel<<<grid, 256, 0, stream>>>(gin, gnz, gout);
}